// Round 8
// baseline (218.246 us; speedup 1.0000x reference)
//
#include <hip/hip_runtime.h>
#include <stdint.h>

// Workspace byte offsets
#define OFF_W1  0        // 1024*32 u32 packed sign bits (784 bits + zero pad)
#define OFF_W2  131072
#define OFF_W3  262144
#define OFF_WFC 393216   // 10*32 u32
#define OFF_T1  395264   // 1024 int32 popcount thresholds
#define OFF_T2  399360
#define OFF_T3  403456
#define OFF_SFC 407552   // double: mean|wfc|
#define OFF_A1  409600   // 8192*32 u32 = 1 MB activation bits (ping)
#define OFF_A2  1458176  // 1 MB (pong)
#define WS_NEED_SPLIT 2506752u   // OFF_A2 + 1 MB
#define RWS 8            // rows/block in fallback fused kernel

// ---------------------------------------------------------------------------
// Prep: one 256-thr BLOCK per output channel. Pack weight sign bits
// (bit=1 <=> w>=0, sign(0)=+1) + integer thresholds in double:
//   dot = K - 2p ;  layer+BN+sign == (p <= Tint[o])
// ---------------------------------------------------------------------------
__global__ __launch_bounds__(256) void bnn_prep(
    const float* __restrict__ w1, const float* __restrict__ b1, const float* __restrict__ g1,
    const float* __restrict__ be1, const float* __restrict__ m1, const float* __restrict__ v1,
    const float* __restrict__ w2, const float* __restrict__ b2, const float* __restrict__ g2,
    const float* __restrict__ be2, const float* __restrict__ m2, const float* __restrict__ v2,
    const float* __restrict__ w3, const float* __restrict__ b3, const float* __restrict__ g3,
    const float* __restrict__ be3, const float* __restrict__ m3, const float* __restrict__ v3,
    const float* __restrict__ wfc,
    uint32_t* __restrict__ ws)
{
    const int t    = threadIdx.x;
    const int lane = t & 63;
    const int wv   = t >> 6;
    const int blk  = blockIdx.x;
    __shared__ double red[4];

    if (blk < 3072) {
        const int l = blk >> 10;
        const int o = blk & 1023;
        const float *w, *bb, *g, *be, *m, *v;
        int K; uint32_t* Wp; int* T;
        if (l == 0)      { w=w1; bb=b1; g=g1; be=be1; m=m1; v=v1; K=784;  Wp = ws + OFF_W1/4; T = (int*)(ws + OFF_T1/4); }
        else if (l == 1) { w=w2; bb=b2; g=g2; be=be2; m=m2; v=v2; K=1024; Wp = ws + OFF_W2/4; T = (int*)(ws + OFF_T2/4); }
        else             { w=w3; bb=b3; g=g3; be=be3; m=m3; v=v3; K=1024; Wp = ws + OFF_W3/4; T = (int*)(ws + OFF_T3/4); }

        const float* wr = w + (size_t)o * K;
        double s = 0.0;
        #pragma unroll
        for (int iter = 0; iter < 4; ++iter) {
            int idx = iter * 256 + t;
            bool inb = idx < K;
            float wval = inb ? wr[idx] : -1.0f;           // OOB -> bit 0
            if (inb) s += fabs((double)wval);
            unsigned long long mask = __ballot(inb && (wval >= 0.0f));
            if (lane == 0)
                *(uint64_t*)(Wp + (size_t)o * 32 + iter * 8 + wv * 2) = mask;
        }
        #pragma unroll
        for (int off = 32; off > 0; off >>= 1) s += __shfl_down(s, off, 64);
        if (lane == 0) red[wv] = s;
        __syncthreads();
        if (t == 0) {
            double sum = red[0] + red[1] + red[2] + red[3];
            double scale = sum / (double)K;
            double r = (double)g[o] / sqrt((double)v[o] + 1e-5);
            double tt = (((double)m[o] - (double)bb[o]) * r - (double)be[o]) / (scale * r);
            double C  = ceil(tt);
            double Td = floor(((double)K - C) * 0.5);
            Td = fmax(fmin(Td, 100000.0), -1.0);
            T[o] = (int)Td;
        }
    } else {
        uint32_t* Wp = ws + OFF_WFC/4;
        double s = 0.0;
        for (int rr = 0; rr < 10; ++rr) {
            const float* wr = wfc + rr * 1024;
            #pragma unroll
            for (int iter = 0; iter < 4; ++iter) {
                int idx = iter * 256 + t;
                float wval = wr[idx];
                s += fabs((double)wval);
                unsigned long long mask = __ballot(wval >= 0.0f);
                if (lane == 0)
                    *(uint64_t*)(Wp + rr * 32 + iter * 8 + wv * 2) = mask;
            }
        }
        #pragma unroll
        for (int off = 32; off > 0; off >>= 1) s += __shfl_down(s, off, 64);
        if (lane == 0) red[wv] = s;
        __syncthreads();
        if (t == 0)
            *(double*)(ws + OFF_SFC/4) = (red[0] + red[1] + red[2] + red[3]) / 10240.0;
    }
}

// ---------------------------------------------------------------------------
// SPLIT PATH (needs ws >= 2.51 MB): layer kernels with lane = batch row.
// Grid 256 = 128 rowgroups x 2 chgroups, block 1024 thr (16 waves), 1 blk/CU.
// Wave wv of block (rg,cg) computes channels [32*(16cg+wv), +32) for rows
// [64rg,+64). W is WAVE-UNIFORM -> streamed through SGPRs via s_load (scalar
// pipe: zero VALU slots, zero vector-L1 traffic, free operand in v_xor).
// Only A[32] per-lane bits live in VGPRs — no allocator fight (R1-R6 lesson:
// per-lane W in VGPRs always got rematerialized -> 89us L2-BW plateau).
// Each lane builds its 32 output bits locally -> no ballots/LDS exchange.
// Kernel boundary = the inter-layer sync. Bounds: actOut max index
// 8191*32+31 = 262143 u32 = 1 MB - 4 B ✓.
// ---------------------------------------------------------------------------
__global__ __launch_bounds__(1024) void bnn_layer1(
    const float* __restrict__ x,
    const uint32_t* __restrict__ ws,
    uint32_t* __restrict__ actOut)
{
    __shared__ uint64_t pk[64][17];     // 64 rows x (16 u64 + 1 pad) = 8704 B
    const int t    = threadIdx.x;
    const int lane = t & 63;
    const int wv   = t >> 6;            // 0..15
    const int rg   = blockIdx.x >> 1;
    const int cg   = blockIdx.x & 1;
    const int row0 = rg * 64;

    // pack 64 rows of x into bits: wave wv packs rows 4wv..4wv+3
    #pragma unroll
    for (int q = 0; q < 4; ++q) {
        const int r = 4 * wv + q;
        const float* xr = x + (size_t)(row0 + r) * 784;
        #pragma unroll
        for (int k = 0; k < 13; ++k) {
            const int idx = k * 64 + lane;
            const bool bit = (idx < 784) && (xr[idx] >= 0.5f);
            unsigned long long m = __ballot(bit);
            if (lane == 0) pk[r][k] = m;
        }
        if (lane == 0) { pk[r][13] = 0; pk[r][14] = 0; pk[r][15] = 0; }
    }
    __syncthreads();

    uint32_t A[32];
    #pragma unroll
    for (int i = 0; i < 16; ++i) {
        uint64_t v = pk[lane][i];
        A[2*i]   = (uint32_t)v;
        A[2*i+1] = (uint32_t)(v >> 32);
    }

    const int slice = __builtin_amdgcn_readfirstlane(16 * cg + wv);  // 0..31
    const uint32_t* Wl = ws + OFF_W1/4;
    const int*      Tl = (const int*)(ws + OFF_T1/4);

    uint32_t outw = 0;
    #pragma unroll 2
    for (int c = 0; c < 32; ++c) {
        const int o = slice * 32 + c;
        const uint32_t* wp = Wl + (o << 5);   // wave-uniform -> s_load
        int p = 0;
        #pragma unroll
        for (int i = 0; i < 32; ++i) p += __popc(A[i] ^ wp[i]);
        outw |= (p <= Tl[o]) ? (1u << c) : 0u;
    }
    actOut[(size_t)(row0 + lane) * 32 + slice] = outw;
}

__global__ __launch_bounds__(1024) void bnn_layerN(
    const uint32_t* __restrict__ actIn,
    const uint32_t* __restrict__ W,
    const int* __restrict__ T,
    uint32_t* __restrict__ actOut)
{
    const int t    = threadIdx.x;
    const int lane = t & 63;
    const int wv   = t >> 6;
    const int rg   = blockIdx.x >> 1;
    const int cg   = blockIdx.x & 1;
    const int row  = rg * 64 + lane;

    uint32_t A[32];
    const uint4* ap = (const uint4*)(actIn + (size_t)row * 32);
    #pragma unroll
    for (int i = 0; i < 8; ++i) ((uint4*)A)[i] = ap[i];

    const int slice = __builtin_amdgcn_readfirstlane(16 * cg + wv);

    uint32_t outw = 0;
    #pragma unroll 2
    for (int c = 0; c < 32; ++c) {
        const int o = slice * 32 + c;
        const uint32_t* wp = W + (o << 5);    // wave-uniform -> s_load
        int p = 0;
        #pragma unroll
        for (int i = 0; i < 32; ++i) p += __popc(A[i] ^ wp[i]);
        outw |= (p <= T[o]) ? (1u << c) : 0u;
    }
    actOut[(size_t)row * 32 + slice] = outw;
}

// FC: lane = row; 10 channels with scalar W. out = (1024-2p)*sfc + bfc[c].
__global__ __launch_bounds__(64) void bnn_fc(
    const uint32_t* __restrict__ act3,
    const uint32_t* __restrict__ ws,
    const float* __restrict__ bfc,
    float* __restrict__ out)
{
    const int lane = threadIdx.x;
    const int row  = blockIdx.x * 64 + lane;

    uint32_t A[32];
    const uint4* ap = (const uint4*)(act3 + (size_t)row * 32);
    #pragma unroll
    for (int i = 0; i < 8; ++i) ((uint4*)A)[i] = ap[i];

    const float sfc = (float)(*(const double*)(ws + OFF_SFC/4));
    const uint32_t* Wfc = ws + OFF_WFC/4;
    #pragma unroll
    for (int ch = 0; ch < 10; ++ch) {
        const uint32_t* wp = Wfc + ch * 32;
        int p = 0;
        #pragma unroll
        for (int i = 0; i < 32; ++i) p += __popc(A[i] ^ wp[i]);
        out[(size_t)row * 10 + ch] = (float)(1024 - 2 * p) * sfc + bfc[ch];
    }
}

// ---------------------------------------------------------------------------
// FALLBACK fused kernel (R4, measured 89.5us; ws need = 408 KB only).
// Used when ws_size is too small for the split path's activation buffers.
// ---------------------------------------------------------------------------
__global__ __launch_bounds__(512, 4) void bnn_fused(
    const float* __restrict__ x,
    const uint32_t* __restrict__ ws,
    const float* __restrict__ bfc,
    float* __restrict__ out)
{
    __shared__ alignas(16) uint32_t bufA[RWS][32];
    __shared__ alignas(16) uint32_t bufB[RWS][32];
    const int t    = threadIdx.x;
    const int lane = t & 63;
    const int wv   = t >> 6;
    const int row0 = blockIdx.x * RWS;

    {
        const float* xr = x + (size_t)(row0 + wv) * 784;
        #pragma unroll
        for (int k = 0; k < 13; ++k) {
            const int idx = k * 64 + lane;
            const bool bit = (idx < 784) && (xr[idx] >= 0.5f);
            unsigned long long m = __ballot(bit);
            if (lane == 0) *(uint64_t*)(&bufA[wv][2 * k]) = m;
        }
        if (lane == 0) {
            *(uint64_t*)(&bufA[wv][26]) = 0ull;
            *(uint64_t*)(&bufA[wv][28]) = 0ull;
            *(uint64_t*)(&bufA[wv][30]) = 0ull;
        }
    }
    __syncthreads();

    const uint32_t* Wbase[3] = { ws + OFF_W1/4, ws + OFF_W2/4, ws + OFF_W3/4 };
    const int*      Tbase[3] = { (const int*)(ws + OFF_T1/4), (const int*)(ws + OFF_T2/4), (const int*)(ws + OFF_T3/4) };

    uint32_t (*cur)[32] = bufA;
    uint32_t (*nxt)[32] = bufB;
    const int c0 = t, c1 = t + 512;

    for (int l = 0; l < 3; ++l) {
        uint32_t W0[32], W1[32];
        {
            const uint4* p0 = (const uint4*)(Wbase[l] + (size_t)c0 * 32);
            const uint4* p1 = (const uint4*)(Wbase[l] + (size_t)c1 * 32);
            #pragma unroll
            for (int i = 0; i < 8; ++i) { ((uint4*)W0)[i] = p0[i]; ((uint4*)W1)[i] = p1[i]; }
        }
        const int T0 = Tbase[l][c0];
        const int T1 = Tbase[l][c1];

        for (int r = 0; r < RWS; ++r) {
            uint32_t A[32];
            #pragma unroll
            for (int i = 0; i < 8; ++i) ((uint4*)A)[i] = ((const uint4*)cur[r])[i];
            int pa = 0, pb = 0, pc = 0, pd = 0;
            #pragma unroll
            for (int i = 0; i < 16; ++i) {
                pa += __popc(A[i]      ^ W0[i]);
                pb += __popc(A[i + 16] ^ W0[i + 16]);
                pc += __popc(A[i]      ^ W1[i]);
                pd += __popc(A[i + 16] ^ W1[i + 16]);
            }
            unsigned long long m0 = __ballot((pa + pb) <= T0);
            unsigned long long m1 = __ballot((pc + pd) <= T1);
            if (lane == 0) {
                *(uint64_t*)(&nxt[r][2 * wv])      = m0;
                *(uint64_t*)(&nxt[r][16 + 2 * wv]) = m1;
            }
        }
        __syncthreads();
        uint32_t (*tmp)[32] = cur; cur = nxt; nxt = tmp;
    }

    if (t < RWS * 10) {
        const float sfc = (float)(*(const double*)(ws + OFF_SFC/4));
        const uint32_t* Wfc = ws + OFF_WFC/4;
        const int r = t / 10, ch = t % 10;
        const uint32_t* wrow = Wfc + ch * 32;
        int p = 0;
        #pragma unroll
        for (int i = 0; i < 32; ++i) p += __popc(cur[r][i] ^ wrow[i]);
        out[(size_t)(row0 + r) * 10 + ch] = (float)(1024 - 2 * p) * sfc + bfc[ch];
    }
}

extern "C" void kernel_launch(void* const* d_in, const int* in_sizes, int n_in,
                              void* d_out, int out_size, void* d_ws, size_t ws_size,
                              hipStream_t stream) {
    const float* x   = (const float*)d_in[0];
    const float* w1  = (const float*)d_in[1];
    const float* b1  = (const float*)d_in[2];
    const float* g1  = (const float*)d_in[3];
    const float* be1 = (const float*)d_in[4];
    const float* m1  = (const float*)d_in[5];
    const float* v1  = (const float*)d_in[6];
    const float* w2  = (const float*)d_in[7];
    const float* b2  = (const float*)d_in[8];
    const float* g2  = (const float*)d_in[9];
    const float* be2 = (const float*)d_in[10];
    const float* m2  = (const float*)d_in[11];
    const float* v2  = (const float*)d_in[12];
    const float* w3  = (const float*)d_in[13];
    const float* b3  = (const float*)d_in[14];
    const float* g3  = (const float*)d_in[15];
    const float* be3 = (const float*)d_in[16];
    const float* m3  = (const float*)d_in[17];
    const float* v3  = (const float*)d_in[18];
    const float* wfc = (const float*)d_in[19];
    const float* bfc = (const float*)d_in[20];
    uint32_t* ws = (uint32_t*)d_ws;
    float* out = (float*)d_out;

    bnn_prep<<<3073, 256, 0, stream>>>(w1, b1, g1, be1, m1, v1,
                                       w2, b2, g2, be2, m2, v2,
                                       w3, b3, g3, be3, m3, v3,
                                       wfc, ws);

    if (ws_size >= (size_t)WS_NEED_SPLIT) {
        uint32_t* a1 = ws + OFF_A1/4;
        uint32_t* a2 = ws + OFF_A2/4;
        bnn_layer1<<<256, 1024, 0, stream>>>(x, ws, a1);
        bnn_layerN<<<256, 1024, 0, stream>>>(a1, ws + OFF_W2/4, (const int*)(ws + OFF_T2/4), a2);
        bnn_layerN<<<256, 1024, 0, stream>>>(a2, ws + OFF_W3/4, (const int*)(ws + OFF_T3/4), a1);
        bnn_fc<<<128, 64, 0, stream>>>(a1, ws, bfc, out);
    } else {
        bnn_fused<<<8192 / RWS, 512, 0, stream>>>(x, ws, bfc, out);
    }
}

// Round 9
// 206.898 us; speedup vs baseline: 1.0548x; 1.0548x over previous
//
#include <hip/hip_runtime.h>
#include <stdint.h>

// Workspace byte offsets
#define OFF_W1  0        // 1024*32 u32 packed sign bits (784 bits + zero pad)
#define OFF_W2  131072
#define OFF_W3  262144
#define OFF_WFC 393216   // 10*32 u32
#define OFF_T1  395264   // 1024 int32 popcount thresholds
#define OFF_T2  399360
#define OFF_T3  403456
#define OFF_SFC 407552   // double: mean|wfc|
#define OFF_P   409600   // 1 MB bit buffer (ping): packed x, then act2
#define OFF_Q   1458176  // 1 MB bit buffer (pong): act1, then act3
#define WS_NEED_SPLIT 2506752u   // == R8's proven-OK size
#define RWS 8            // rows/block in fallback fused kernel

// ---------------------------------------------------------------------------
// Prep: one 256-thr BLOCK per output channel. Pack weight sign bits
// (bit=1 <=> w>=0, sign(0)=+1) + integer thresholds in double:
//   dot = K - 2p ;  layer+BN+sign == (p <= Tint[o])
// ---------------------------------------------------------------------------
__global__ __launch_bounds__(256) void bnn_prep(
    const float* __restrict__ w1, const float* __restrict__ b1, const float* __restrict__ g1,
    const float* __restrict__ be1, const float* __restrict__ m1, const float* __restrict__ v1,
    const float* __restrict__ w2, const float* __restrict__ b2, const float* __restrict__ g2,
    const float* __restrict__ be2, const float* __restrict__ m2, const float* __restrict__ v2,
    const float* __restrict__ w3, const float* __restrict__ b3, const float* __restrict__ g3,
    const float* __restrict__ be3, const float* __restrict__ m3, const float* __restrict__ v3,
    const float* __restrict__ wfc,
    uint32_t* __restrict__ ws)
{
    const int t    = threadIdx.x;
    const int lane = t & 63;
    const int wv   = t >> 6;
    const int blk  = blockIdx.x;
    __shared__ double red[4];

    if (blk < 3072) {
        const int l = blk >> 10;
        const int o = blk & 1023;
        const float *w, *bb, *g, *be, *m, *v;
        int K; uint32_t* Wp; int* T;
        if (l == 0)      { w=w1; bb=b1; g=g1; be=be1; m=m1; v=v1; K=784;  Wp = ws + OFF_W1/4; T = (int*)(ws + OFF_T1/4); }
        else if (l == 1) { w=w2; bb=b2; g=g2; be=be2; m=m2; v=v2; K=1024; Wp = ws + OFF_W2/4; T = (int*)(ws + OFF_T2/4); }
        else             { w=w3; bb=b3; g=g3; be=be3; m=m3; v=v3; K=1024; Wp = ws + OFF_W3/4; T = (int*)(ws + OFF_T3/4); }

        const float* wr = w + (size_t)o * K;
        double s = 0.0;
        #pragma unroll
        for (int iter = 0; iter < 4; ++iter) {
            int idx = iter * 256 + t;
            bool inb = idx < K;
            float wval = inb ? wr[idx] : -1.0f;           // OOB -> bit 0
            if (inb) s += fabs((double)wval);
            unsigned long long mask = __ballot(inb && (wval >= 0.0f));
            if (lane == 0)
                *(uint64_t*)(Wp + (size_t)o * 32 + iter * 8 + wv * 2) = mask;
        }
        #pragma unroll
        for (int off = 32; off > 0; off >>= 1) s += __shfl_down(s, off, 64);
        if (lane == 0) red[wv] = s;
        __syncthreads();
        if (t == 0) {
            double sum = red[0] + red[1] + red[2] + red[3];
            double scale = sum / (double)K;
            double r = (double)g[o] / sqrt((double)v[o] + 1e-5);
            double tt = (((double)m[o] - (double)bb[o]) * r - (double)be[o]) / (scale * r);
            double C  = ceil(tt);
            double Td = floor(((double)K - C) * 0.5);
            Td = fmax(fmin(Td, 100000.0), -1.0);
            T[o] = (int)Td;
        }
    } else {
        uint32_t* Wp = ws + OFF_WFC/4;
        double s = 0.0;
        for (int rr = 0; rr < 10; ++rr) {
            const float* wr = wfc + rr * 1024;
            #pragma unroll
            for (int iter = 0; iter < 4; ++iter) {
                int idx = iter * 256 + t;
                float wval = wr[idx];
                s += fabs((double)wval);
                unsigned long long mask = __ballot(wval >= 0.0f);
                if (lane == 0)
                    *(uint64_t*)(Wp + rr * 32 + iter * 8 + wv * 2) = mask;
            }
        }
        #pragma unroll
        for (int off = 32; off > 0; off >>= 1) s += __shfl_down(s, off, 64);
        if (lane == 0) red[wv] = s;
        __syncthreads();
        if (t == 0)
            *(double*)(ws + OFF_SFC/4) = (red[0] + red[1] + red[2] + red[3]) / 10240.0;
    }
}

// ---------------------------------------------------------------------------
// Pack x into bits, one THREAD per output u32 word (no ballots, no cross-lane
// dependency -> pure BW). gid = r*32 + w; bit j of word w = (x[r][32w+j]>=0.5)
// (+1 <=> 2x-1>=0). Words 24 partial (16 bits), 25..31 zero (matches W1 pad).
// Grid 1024 x 256. Coalesced float4 loads; coalesced u32 stores.
// ---------------------------------------------------------------------------
__global__ __launch_bounds__(256) void bnn_pack(
    const float* __restrict__ x,
    uint32_t* __restrict__ xp)
{
    const int gid = blockIdx.x * 256 + threadIdx.x;   // 0..262143
    const int r = gid >> 5;
    const int w = gid & 31;

    uint32_t bits = 0;
    if (w < 24) {
        const float4* p = (const float4*)(x + (size_t)r * 784 + 32 * w);
        #pragma unroll
        for (int i = 0; i < 8; ++i) {
            float4 v = p[i];
            bits |= (v.x >= 0.5f) ? (1u << (4*i))     : 0u;
            bits |= (v.y >= 0.5f) ? (1u << (4*i + 1)) : 0u;
            bits |= (v.z >= 0.5f) ? (1u << (4*i + 2)) : 0u;
            bits |= (v.w >= 0.5f) ? (1u << (4*i + 3)) : 0u;
        }
    } else if (w == 24) {
        const float4* p = (const float4*)(x + (size_t)r * 784 + 768);
        #pragma unroll
        for (int i = 0; i < 4; ++i) {
            float4 v = p[i];
            bits |= (v.x >= 0.5f) ? (1u << (4*i))     : 0u;
            bits |= (v.y >= 0.5f) ? (1u << (4*i + 1)) : 0u;
            bits |= (v.z >= 0.5f) ? (1u << (4*i + 2)) : 0u;
            bits |= (v.w >= 0.5f) ? (1u << (4*i + 3)) : 0u;
        }
    }
    xp[gid] = bits;
}

// ---------------------------------------------------------------------------
// Layer kernel, lane = batch row. Grid 512 = 128 rowgroups x 4 chgroups,
// block 1024 thr (16 waves) -> 2 blocks/CU = 32 waves/CU (s_load latency
// hidden; R8 ran 1 blk/CU, Occ 35%, layers ~25-48us). Wave handles 16
// channels: slice = 4*... = cg*16+wv in 0..63, channels [16*slice,+16).
// W/T wave-uniform -> scalar pipe. A[32] per-lane. Output: u16 halfword at
// act16[row*64 + slice]; little-endian makes u16 pair (2w,2w+1) == u32 word w
// (channels 32w..32w+31) for the next layer's u32 reads.
// ---------------------------------------------------------------------------
__global__ __launch_bounds__(1024) void bnn_layer(
    const uint32_t* __restrict__ actIn,
    const uint32_t* __restrict__ W,
    const int* __restrict__ T,
    uint32_t* __restrict__ actOut)
{
    const int t    = threadIdx.x;
    const int lane = t & 63;
    const int wv   = t >> 6;            // 0..15
    const int rg   = blockIdx.x >> 2;   // 0..127
    const int cg   = blockIdx.x & 3;    // 0..3
    const int row  = rg * 64 + lane;

    uint32_t A[32];
    const uint4* ap = (const uint4*)(actIn + (size_t)row * 32);
    #pragma unroll
    for (int i = 0; i < 8; ++i) ((uint4*)A)[i] = ap[i];

    const int slice = __builtin_amdgcn_readfirstlane(cg * 16 + wv);   // 0..63

    uint32_t outw = 0;
    #pragma unroll 2
    for (int c = 0; c < 16; ++c) {
        const int o = slice * 16 + c;
        const uint32_t* wp = W + (o << 5);    // wave-uniform -> s_load
        int p = 0;
        #pragma unroll
        for (int i = 0; i < 32; ++i) p += __popc(A[i] ^ wp[i]);
        outw |= (p <= T[o]) ? (1u << c) : 0u;
    }
    ((uint16_t*)actOut)[(size_t)row * 64 + slice] = (uint16_t)outw;
}

// FC: lane = row; 10 channels with scalar W. out = (1024-2p)*sfc + bfc[c].
__global__ __launch_bounds__(64) void bnn_fc(
    const uint32_t* __restrict__ act3,
    const uint32_t* __restrict__ ws,
    const float* __restrict__ bfc,
    float* __restrict__ out)
{
    const int lane = threadIdx.x;
    const int row  = blockIdx.x * 64 + lane;

    uint32_t A[32];
    const uint4* ap = (const uint4*)(act3 + (size_t)row * 32);
    #pragma unroll
    for (int i = 0; i < 8; ++i) ((uint4*)A)[i] = ap[i];

    const float sfc = (float)(*(const double*)(ws + OFF_SFC/4));
    const uint32_t* Wfc = ws + OFF_WFC/4;
    #pragma unroll
    for (int ch = 0; ch < 10; ++ch) {
        const uint32_t* wp = Wfc + ch * 32;
        int p = 0;
        #pragma unroll
        for (int i = 0; i < 32; ++i) p += __popc(A[i] ^ wp[i]);
        out[(size_t)row * 10 + ch] = (float)(1024 - 2 * p) * sfc + bfc[ch];
    }
}

// ---------------------------------------------------------------------------
// FALLBACK fused kernel (R4, measured 89.5us; ws need = 408 KB only).
// ---------------------------------------------------------------------------
__global__ __launch_bounds__(512, 4) void bnn_fused(
    const float* __restrict__ x,
    const uint32_t* __restrict__ ws,
    const float* __restrict__ bfc,
    float* __restrict__ out)
{
    __shared__ alignas(16) uint32_t bufA[RWS][32];
    __shared__ alignas(16) uint32_t bufB[RWS][32];
    const int t    = threadIdx.x;
    const int lane = t & 63;
    const int wv   = t >> 6;
    const int row0 = blockIdx.x * RWS;

    {
        const float* xr = x + (size_t)(row0 + wv) * 784;
        #pragma unroll
        for (int k = 0; k < 13; ++k) {
            const int idx = k * 64 + lane;
            const bool bit = (idx < 784) && (xr[idx] >= 0.5f);
            unsigned long long m = __ballot(bit);
            if (lane == 0) *(uint64_t*)(&bufA[wv][2 * k]) = m;
        }
        if (lane == 0) {
            *(uint64_t*)(&bufA[wv][26]) = 0ull;
            *(uint64_t*)(&bufA[wv][28]) = 0ull;
            *(uint64_t*)(&bufA[wv][30]) = 0ull;
        }
    }
    __syncthreads();

    const uint32_t* Wbase[3] = { ws + OFF_W1/4, ws + OFF_W2/4, ws + OFF_W3/4 };
    const int*      Tbase[3] = { (const int*)(ws + OFF_T1/4), (const int*)(ws + OFF_T2/4), (const int*)(ws + OFF_T3/4) };

    uint32_t (*cur)[32] = bufA;
    uint32_t (*nxt)[32] = bufB;
    const int c0 = t, c1 = t + 512;

    for (int l = 0; l < 3; ++l) {
        uint32_t W0[32], W1[32];
        {
            const uint4* p0 = (const uint4*)(Wbase[l] + (size_t)c0 * 32);
            const uint4* p1 = (const uint4*)(Wbase[l] + (size_t)c1 * 32);
            #pragma unroll
            for (int i = 0; i < 8; ++i) { ((uint4*)W0)[i] = p0[i]; ((uint4*)W1)[i] = p1[i]; }
        }
        const int T0 = Tbase[l][c0];
        const int T1 = Tbase[l][c1];

        for (int r = 0; r < RWS; ++r) {
            uint32_t A[32];
            #pragma unroll
            for (int i = 0; i < 8; ++i) ((uint4*)A)[i] = ((const uint4*)cur[r])[i];
            int pa = 0, pb = 0, pc = 0, pd = 0;
            #pragma unroll
            for (int i = 0; i < 16; ++i) {
                pa += __popc(A[i]      ^ W0[i]);
                pb += __popc(A[i + 16] ^ W0[i + 16]);
                pc += __popc(A[i]      ^ W1[i]);
                pd += __popc(A[i + 16] ^ W1[i + 16]);
            }
            unsigned long long m0 = __ballot((pa + pb) <= T0);
            unsigned long long m1 = __ballot((pc + pd) <= T1);
            if (lane == 0) {
                *(uint64_t*)(&nxt[r][2 * wv])      = m0;
                *(uint64_t*)(&nxt[r][16 + 2 * wv]) = m1;
            }
        }
        __syncthreads();
        uint32_t (*tmp)[32] = cur; cur = nxt; nxt = tmp;
    }

    if (t < RWS * 10) {
        const float sfc = (float)(*(const double*)(ws + OFF_SFC/4));
        const uint32_t* Wfc = ws + OFF_WFC/4;
        const int r = t / 10, ch = t % 10;
        const uint32_t* wrow = Wfc + ch * 32;
        int p = 0;
        #pragma unroll
        for (int i = 0; i < 32; ++i) p += __popc(cur[r][i] ^ wrow[i]);
        out[(size_t)(row0 + r) * 10 + ch] = (float)(1024 - 2 * p) * sfc + bfc[ch];
    }
}

extern "C" void kernel_launch(void* const* d_in, const int* in_sizes, int n_in,
                              void* d_out, int out_size, void* d_ws, size_t ws_size,
                              hipStream_t stream) {
    const float* x   = (const float*)d_in[0];
    const float* w1  = (const float*)d_in[1];
    const float* b1  = (const float*)d_in[2];
    const float* g1  = (const float*)d_in[3];
    const float* be1 = (const float*)d_in[4];
    const float* m1  = (const float*)d_in[5];
    const float* v1  = (const float*)d_in[6];
    const float* w2  = (const float*)d_in[7];
    const float* b2  = (const float*)d_in[8];
    const float* g2  = (const float*)d_in[9];
    const float* be2 = (const float*)d_in[10];
    const float* m2  = (const float*)d_in[11];
    const float* v2  = (const float*)d_in[12];
    const float* w3  = (const float*)d_in[13];
    const float* b3  = (const float*)d_in[14];
    const float* g3  = (const float*)d_in[15];
    const float* be3 = (const float*)d_in[16];
    const float* m3  = (const float*)d_in[17];
    const float* v3  = (const float*)d_in[18];
    const float* wfc = (const float*)d_in[19];
    const float* bfc = (const float*)d_in[20];
    uint32_t* ws = (uint32_t*)d_ws;
    float* out = (float*)d_out;

    bnn_prep<<<3073, 256, 0, stream>>>(w1, b1, g1, be1, m1, v1,
                                       w2, b2, g2, be2, m2, v2,
                                       w3, b3, g3, be3, m3, v3,
                                       wfc, ws);

    if (ws_size >= (size_t)WS_NEED_SPLIT) {
        uint32_t* P = ws + OFF_P/4;
        uint32_t* Q = ws + OFF_Q/4;
        bnn_pack<<<1024, 256, 0, stream>>>(x, P);
        bnn_layer<<<512, 1024, 0, stream>>>(P, ws + OFF_W1/4, (const int*)(ws + OFF_T1/4), Q);
        bnn_layer<<<512, 1024, 0, stream>>>(Q, ws + OFF_W2/4, (const int*)(ws + OFF_T2/4), P);
        bnn_layer<<<512, 1024, 0, stream>>>(P, ws + OFF_W3/4, (const int*)(ws + OFF_T3/4), Q);
        bnn_fc<<<128, 64, 0, stream>>>(Q, ws, bfc, out);
    } else {
        bnn_fused<<<8192 / RWS, 512, 0, stream>>>(x, ws, bfc, out);
    }
}

// Round 10
// 187.612 us; speedup vs baseline: 1.1633x; 1.1028x over previous
//
#include <hip/hip_runtime.h>
#include <stdint.h>

// Workspace byte offsets
#define OFF_W1  0        // 1024*32 u32 packed sign bits (784 bits + zero pad)
#define OFF_W2  131072
#define OFF_W3  262144
#define OFF_WFC 393216   // 10*32 u32
#define OFF_T1  395264   // 1024 int32 popcount thresholds
#define OFF_T2  399360
#define OFF_T3  403456
#define OFF_SFC 407552   // double: mean|wfc|
#define OFF_P   409600   // 1 MB bit buffer (ping): packed x, then act2
#define OFF_Q   1458176  // 1 MB bit buffer (pong): act1, then act3
#define WS_NEED_SPLIT 2506752u
#define RWS 8            // rows/block in fallback fused kernel

typedef uint32_t u32x16 __attribute__((ext_vector_type(16)));

// ---------------------------------------------------------------------------
// Prep v2 — ballot-free, one dispatch does W-pack + thresholds + wfc + x-pack.
//   blocks 0..383   : thread = (layer, channel o, word k); packs 32 weights
//                     into one u32 (bit=1 <=> w>=0, sign(0)=+1) and computes
//                     per-channel mean|w| via half-wave shfl_xor tree (the 32
//                     threads of channel o are lanes [0..31] or [32..63]).
//                     Threshold (double, exact): dot = K-2p; layer+BN+sign
//                     == (p <= Tint[o]).
//   block 384       : wfc pack (320 words) + global mean|wfc| block-reduce.
//   blocks 385..1408: x-pack, thread = one u32 word (R9-verified convention:
//                     bit j of word w = (x[r][32w+j] >= 0.5); words 25..31=0).
// ---------------------------------------------------------------------------
__global__ __launch_bounds__(256) void bnn_prep(
    const float* __restrict__ x,
    const float* __restrict__ w1, const float* __restrict__ b1, const float* __restrict__ g1,
    const float* __restrict__ be1, const float* __restrict__ m1, const float* __restrict__ v1,
    const float* __restrict__ w2, const float* __restrict__ b2, const float* __restrict__ g2,
    const float* __restrict__ be2, const float* __restrict__ m2, const float* __restrict__ v2,
    const float* __restrict__ w3, const float* __restrict__ b3, const float* __restrict__ g3,
    const float* __restrict__ be3, const float* __restrict__ m3, const float* __restrict__ v3,
    const float* __restrict__ wfc,
    uint32_t* __restrict__ ws)
{
    const int blk  = blockIdx.x;
    const int t    = threadIdx.x;
    const int lane = t & 63;
    const int wv   = t >> 6;

    if (blk < 384) {
        const int gid = blk * 256 + t;      // 0..98303
        const int l   = gid >> 15;          // layer 0..2 (32768 words each)
        const int rem = gid & 32767;
        const int o   = rem >> 5;           // channel
        const int k   = rem & 31;           // word within channel
        const float *w, *bb, *g, *be, *m, *v;
        int K; uint32_t* Wp; int* T;
        if (l == 0)      { w=w1; bb=b1; g=g1; be=be1; m=m1; v=v1; K=784;  Wp = ws + OFF_W1/4; T = (int*)(ws + OFF_T1/4); }
        else if (l == 1) { w=w2; bb=b2; g=g2; be=be2; m=m2; v=v2; K=1024; Wp = ws + OFF_W2/4; T = (int*)(ws + OFF_T2/4); }
        else             { w=w3; bb=b3; g=g3; be=be3; m=m3; v=v3; K=1024; Wp = ws + OFF_W3/4; T = (int*)(ws + OFF_T3/4); }

        const int base = 32 * k;
        uint32_t bits = 0;
        double s = 0.0;
        if (base < K) {
            const float4* p = (const float4*)(w + (size_t)o * K + base);
            const int n4 = (K - base >= 32) ? 8 : 4;   // K=784, k=24 -> 16 elems
            for (int i = 0; i < n4; ++i) {
                float4 q = p[i];
                bits |= (q.x >= 0.0f) ? (1u << (4*i + 0)) : 0u;
                bits |= (q.y >= 0.0f) ? (1u << (4*i + 1)) : 0u;
                bits |= (q.z >= 0.0f) ? (1u << (4*i + 2)) : 0u;
                bits |= (q.w >= 0.0f) ? (1u << (4*i + 3)) : 0u;
                s += fabs((double)q.x) + fabs((double)q.y)
                   + fabs((double)q.z) + fabs((double)q.w);
            }
        }
        // half-wave (32-lane) xor tree: all lanes of the half get channel sum
        #pragma unroll
        for (int mask = 1; mask <= 16; mask <<= 1)
            s += __shfl_xor(s, mask, 64);
        if (k == 0) {
            double scale = s / (double)K;                        // mean|w| > 0
            double r = (double)g[o] / sqrt((double)v[o] + 1e-5); // > 0
            double tt = (((double)m[o] - (double)bb[o]) * r - (double)be[o]) / (scale * r);
            double C  = ceil(tt);                                // dot >= C
            double Td = floor(((double)K - C) * 0.5);            // p <= Td
            Td = fmax(fmin(Td, 100000.0), -1.0);
            T[o] = (int)Td;
        }
        Wp[(size_t)o * 32 + k] = bits;
    } else if (blk == 384) {
        // wfc: 320 words (10 ch x 32); thread t does word t and (t<64) t+256
        uint32_t* Wp = ws + OFF_WFC/4;
        double s = 0.0;
        {
            const int o = t >> 5, k = t & 31;
            const float4* p = (const float4*)(wfc + o * 1024 + 32 * k);
            uint32_t bits = 0;
            #pragma unroll
            for (int i = 0; i < 8; ++i) {
                float4 q = p[i];
                bits |= (q.x >= 0.0f) ? (1u << (4*i + 0)) : 0u;
                bits |= (q.y >= 0.0f) ? (1u << (4*i + 1)) : 0u;
                bits |= (q.z >= 0.0f) ? (1u << (4*i + 2)) : 0u;
                bits |= (q.w >= 0.0f) ? (1u << (4*i + 3)) : 0u;
                s += fabs((double)q.x) + fabs((double)q.y)
                   + fabs((double)q.z) + fabs((double)q.w);
            }
            Wp[t] = bits;
        }
        if (t < 64) {
            const int t2 = t + 256;
            const int o = t2 >> 5, k = t2 & 31;
            const float4* p = (const float4*)(wfc + o * 1024 + 32 * k);
            uint32_t bits = 0;
            #pragma unroll
            for (int i = 0; i < 8; ++i) {
                float4 q = p[i];
                bits |= (q.x >= 0.0f) ? (1u << (4*i + 0)) : 0u;
                bits |= (q.y >= 0.0f) ? (1u << (4*i + 1)) : 0u;
                bits |= (q.z >= 0.0f) ? (1u << (4*i + 2)) : 0u;
                bits |= (q.w >= 0.0f) ? (1u << (4*i + 3)) : 0u;
                s += fabs((double)q.x) + fabs((double)q.y)
                   + fabs((double)q.z) + fabs((double)q.w);
            }
            Wp[t2] = bits;
        }
        __shared__ double red[4];
        #pragma unroll
        for (int off = 32; off > 0; off >>= 1) s += __shfl_down(s, off, 64);
        if (lane == 0) red[wv] = s;
        __syncthreads();
        if (t == 0)
            *(double*)(ws + OFF_SFC/4) = (red[0] + red[1] + red[2] + red[3]) / 10240.0;
    } else {
        // x-pack (split path only): gid = one u32 word
        const int gid = (blk - 385) * 256 + t;   // 0..262143
        const int r = gid >> 5;
        const int w = gid & 31;
        uint32_t bits = 0;
        if (w < 24) {
            const float4* p = (const float4*)(x + (size_t)r * 784 + 32 * w);
            #pragma unroll
            for (int i = 0; i < 8; ++i) {
                float4 q = p[i];
                bits |= (q.x >= 0.5f) ? (1u << (4*i + 0)) : 0u;
                bits |= (q.y >= 0.5f) ? (1u << (4*i + 1)) : 0u;
                bits |= (q.z >= 0.5f) ? (1u << (4*i + 2)) : 0u;
                bits |= (q.w >= 0.5f) ? (1u << (4*i + 3)) : 0u;
            }
        } else if (w == 24) {
            const float4* p = (const float4*)(x + (size_t)r * 784 + 768);
            #pragma unroll
            for (int i = 0; i < 4; ++i) {
                float4 q = p[i];
                bits |= (q.x >= 0.5f) ? (1u << (4*i + 0)) : 0u;
                bits |= (q.y >= 0.5f) ? (1u << (4*i + 1)) : 0u;
                bits |= (q.z >= 0.5f) ? (1u << (4*i + 2)) : 0u;
                bits |= (q.w >= 0.5f) ? (1u << (4*i + 3)) : 0u;
            }
        }
        (ws + OFF_P/4)[gid] = bits;
    }
}

// ---------------------------------------------------------------------------
// Layer kernel, lane = batch row, W streamed through the SCALAR pipe via
// inline-asm s_load_dwordx16 (R8/R9 evidence: relying on uniformity analysis
// left layers at ~30us ≈ the L1-broadcast-return bound of vector loads of a
// uniform address; forced s_load makes W cost ~0 VALU/VMEM -> VALU-bound
// ~8us). Grid 512 = 128 rowgroups x 4 chgroups, block 1024 (16 waves).
// Wave = 16 channels: slice = cg*16+wv in 0..63; A[32] per-lane bits; output
// u16 at act16[row*64+slice] (little-endian: u16 pair == u32 word).
// ---------------------------------------------------------------------------
__global__ __launch_bounds__(1024) void bnn_layer(
    const uint32_t* __restrict__ actIn,
    const uint32_t* __restrict__ W,
    const int* __restrict__ T,
    uint32_t* __restrict__ actOut)
{
    const int t    = threadIdx.x;
    const int lane = t & 63;
    const int wv   = t >> 6;            // 0..15
    const int rg   = blockIdx.x >> 2;   // 0..127
    const int cg   = blockIdx.x & 3;    // 0..3
    const int row  = rg * 64 + lane;

    uint32_t A[32];
    const uint4* ap = (const uint4*)(actIn + (size_t)row * 32);
    #pragma unroll
    for (int i = 0; i < 8; ++i) ((uint4*)A)[i] = ap[i];

    const int slice = __builtin_amdgcn_readfirstlane(cg * 16 + wv);   // 0..63

    // thresholds for our 16 channels: one scalar x16 load
    u32x16 tv;
    {
        const int* tp = T + slice * 16;
        asm volatile("s_load_dwordx16 %0, %1, 0x0\n\t"
                     "s_waitcnt lgkmcnt(0)"
                     : "=s"(tv) : "s"(tp));
    }

    uint32_t outw = 0;
    #pragma unroll
    for (int c = 0; c < 16; ++c) {
        const uint32_t* wp = W + (((size_t)slice * 16 + c) << 5);
        u32x16 wlo, whi;
        asm volatile("s_load_dwordx16 %0, %2, 0x0\n\t"
                     "s_load_dwordx16 %1, %2, 0x40\n\t"
                     "s_waitcnt lgkmcnt(0)"
                     : "=s"(wlo), "=s"(whi) : "s"(wp));
        int pa = 0, pb = 0;
        #pragma unroll
        for (int i = 0; i < 16; ++i) {
            pa += __popc(A[i]      ^ wlo[i]);
            pb += __popc(A[i + 16] ^ whi[i]);
        }
        outw |= ((pa + pb) <= (int)tv[c]) ? (1u << c) : 0u;
    }
    ((uint16_t*)actOut)[(size_t)row * 64 + slice] = (uint16_t)outw;
}

// FC: lane = row; 10 channels. out = (1024-2p)*sfc + bfc[c] (exact int dot).
__global__ __launch_bounds__(64) void bnn_fc(
    const uint32_t* __restrict__ act3,
    const uint32_t* __restrict__ ws,
    const float* __restrict__ bfc,
    float* __restrict__ out)
{
    const int lane = threadIdx.x;
    const int row  = blockIdx.x * 64 + lane;

    uint32_t A[32];
    const uint4* ap = (const uint4*)(act3 + (size_t)row * 32);
    #pragma unroll
    for (int i = 0; i < 8; ++i) ((uint4*)A)[i] = ap[i];

    const float sfc = (float)(*(const double*)(ws + OFF_SFC/4));
    const uint32_t* Wfc = ws + OFF_WFC/4;
    #pragma unroll
    for (int ch = 0; ch < 10; ++ch) {
        const uint32_t* wp = Wfc + ch * 32;
        int p = 0;
        #pragma unroll
        for (int i = 0; i < 32; ++i) p += __popc(A[i] ^ wp[i]);
        out[(size_t)row * 10 + ch] = (float)(1024 - 2 * p) * sfc + bfc[ch];
    }
}

// ---------------------------------------------------------------------------
// FALLBACK fused kernel (R4, 89.5us; ws need 408 KB) — used if ws too small.
// ---------------------------------------------------------------------------
__global__ __launch_bounds__(512, 4) void bnn_fused(
    const float* __restrict__ x,
    const uint32_t* __restrict__ ws,
    const float* __restrict__ bfc,
    float* __restrict__ out)
{
    __shared__ alignas(16) uint32_t bufA[RWS][32];
    __shared__ alignas(16) uint32_t bufB[RWS][32];
    const int t    = threadIdx.x;
    const int lane = t & 63;
    const int wv   = t >> 6;
    const int row0 = blockIdx.x * RWS;

    {
        const float* xr = x + (size_t)(row0 + wv) * 784;
        #pragma unroll
        for (int k = 0; k < 13; ++k) {
            const int idx = k * 64 + lane;
            const bool bit = (idx < 784) && (xr[idx] >= 0.5f);
            unsigned long long m = __ballot(bit);
            if (lane == 0) *(uint64_t*)(&bufA[wv][2 * k]) = m;
        }
        if (lane == 0) {
            *(uint64_t*)(&bufA[wv][26]) = 0ull;
            *(uint64_t*)(&bufA[wv][28]) = 0ull;
            *(uint64_t*)(&bufA[wv][30]) = 0ull;
        }
    }
    __syncthreads();

    const uint32_t* Wbase[3] = { ws + OFF_W1/4, ws + OFF_W2/4, ws + OFF_W3/4 };
    const int*      Tbase[3] = { (const int*)(ws + OFF_T1/4), (const int*)(ws + OFF_T2/4), (const int*)(ws + OFF_T3/4) };

    uint32_t (*cur)[32] = bufA;
    uint32_t (*nxt)[32] = bufB;
    const int c0 = t, c1 = t + 512;

    for (int l = 0; l < 3; ++l) {
        uint32_t W0[32], W1[32];
        {
            const uint4* p0 = (const uint4*)(Wbase[l] + (size_t)c0 * 32);
            const uint4* p1 = (const uint4*)(Wbase[l] + (size_t)c1 * 32);
            #pragma unroll
            for (int i = 0; i < 8; ++i) { ((uint4*)W0)[i] = p0[i]; ((uint4*)W1)[i] = p1[i]; }
        }
        const int T0 = Tbase[l][c0];
        const int T1 = Tbase[l][c1];

        for (int r = 0; r < RWS; ++r) {
            uint32_t A[32];
            #pragma unroll
            for (int i = 0; i < 8; ++i) ((uint4*)A)[i] = ((const uint4*)cur[r])[i];
            int pa = 0, pb = 0, pc = 0, pd = 0;
            #pragma unroll
            for (int i = 0; i < 16; ++i) {
                pa += __popc(A[i]      ^ W0[i]);
                pb += __popc(A[i + 16] ^ W0[i + 16]);
                pc += __popc(A[i]      ^ W1[i]);
                pd += __popc(A[i + 16] ^ W1[i + 16]);
            }
            unsigned long long m0 = __ballot((pa + pb) <= T0);
            unsigned long long m1 = __ballot((pc + pd) <= T1);
            if (lane == 0) {
                *(uint64_t*)(&nxt[r][2 * wv])      = m0;
                *(uint64_t*)(&nxt[r][16 + 2 * wv]) = m1;
            }
        }
        __syncthreads();
        uint32_t (*tmp)[32] = cur; cur = nxt; nxt = tmp;
    }

    if (t < RWS * 10) {
        const float sfc = (float)(*(const double*)(ws + OFF_SFC/4));
        const uint32_t* Wfc = ws + OFF_WFC/4;
        const int r = t / 10, ch = t % 10;
        const uint32_t* wrow = Wfc + ch * 32;
        int p = 0;
        #pragma unroll
        for (int i = 0; i < 32; ++i) p += __popc(cur[r][i] ^ wrow[i]);
        out[(size_t)(row0 + r) * 10 + ch] = (float)(1024 - 2 * p) * sfc + bfc[ch];
    }
}

extern "C" void kernel_launch(void* const* d_in, const int* in_sizes, int n_in,
                              void* d_out, int out_size, void* d_ws, size_t ws_size,
                              hipStream_t stream) {
    const float* x   = (const float*)d_in[0];
    const float* w1  = (const float*)d_in[1];
    const float* b1  = (const float*)d_in[2];
    const float* g1  = (const float*)d_in[3];
    const float* be1 = (const float*)d_in[4];
    const float* m1  = (const float*)d_in[5];
    const float* v1  = (const float*)d_in[6];
    const float* w2  = (const float*)d_in[7];
    const float* b2  = (const float*)d_in[8];
    const float* g2  = (const float*)d_in[9];
    const float* be2 = (const float*)d_in[10];
    const float* m2  = (const float*)d_in[11];
    const float* v2  = (const float*)d_in[12];
    const float* w3  = (const float*)d_in[13];
    const float* b3  = (const float*)d_in[14];
    const float* g3  = (const float*)d_in[15];
    const float* be3 = (const float*)d_in[16];
    const float* m3  = (const float*)d_in[17];
    const float* v3  = (const float*)d_in[18];
    const float* wfc = (const float*)d_in[19];
    const float* bfc = (const float*)d_in[20];
    uint32_t* ws = (uint32_t*)d_ws;
    float* out = (float*)d_out;

    const bool split = (ws_size >= (size_t)WS_NEED_SPLIT);

    // blocks: 385 weight/wfc blocks (+1024 x-pack blocks on the split path)
    bnn_prep<<<split ? 1409 : 385, 256, 0, stream>>>(
        x,
        w1, b1, g1, be1, m1, v1,
        w2, b2, g2, be2, m2, v2,
        w3, b3, g3, be3, m3, v3,
        wfc, ws);

    if (split) {
        uint32_t* P = ws + OFF_P/4;
        uint32_t* Q = ws + OFF_Q/4;
        bnn_layer<<<512, 1024, 0, stream>>>(P, ws + OFF_W1/4, (const int*)(ws + OFF_T1/4), Q);
        bnn_layer<<<512, 1024, 0, stream>>>(Q, ws + OFF_W2/4, (const int*)(ws + OFF_T2/4), P);
        bnn_layer<<<512, 1024, 0, stream>>>(P, ws + OFF_W3/4, (const int*)(ws + OFF_T3/4), Q);
        bnn_fc<<<128, 64, 0, stream>>>(Q, ws, bfc, out);
    } else {
        bnn_fused<<<8192 / RWS, 512, 0, stream>>>(x, ws, bfc, out);
    }
}